// Round 1
// 910.426 us; speedup vs baseline: 1.0449x; 1.0449x over previous
//
#include <hip/hip_runtime.h>

#define KREAL 19000
#define KP    19008      // K padded to multiple of 32
#define NSTEPS 594       // KP / 32
#define BM 128
#define BN 256
#define MBLK 64          // 8192 / BM
#define BATCH 8192
#define SDIM 256
#define PDIM 128

typedef __attribute__((ext_vector_type(8))) short frag_ab;   // 8 bf16 = 4 VGPRs
typedef __attribute__((ext_vector_type(4))) float frag_cd;   // 4 fp32 acc

static __device__ __forceinline__ short f2bf(float f) {
    union { float f; unsigned u; } cv; cv.f = f;
    unsigned u = cv.u;
    u += 0x7fffu + ((u >> 16) & 1u);   // round-to-nearest-even
    return (short)(u >> 16);
}

static __device__ __forceinline__ short4 cvt4(float4 v) {
    short4 p;
    p.x = f2bf(v.x); p.y = f2bf(v.y); p.z = f2bf(v.z); p.w = f2bf(v.w);
    return p;
}

// ---------------------------------------------------------------------------
// Kernel 0: W1 [19000][256] fp32  ->  W1t [256][19008] bf16 (zero-padded K)
// ---------------------------------------------------------------------------
__global__ void transpose_w1(const float* __restrict__ W1, short* __restrict__ W1t) {
    __shared__ float tile[32][33];
    int k0 = blockIdx.x * 32;
    int n0 = blockIdx.y * 32;
    int tx = threadIdx.x & 31;
    int ty = threadIdx.x >> 5;           // 0..7
#pragma unroll
    for (int i = 0; i < 32; i += 8) {
        int k = k0 + ty + i;
        tile[ty + i][tx] = (k < KREAL) ? W1[(long)k * SDIM + n0 + tx] : 0.f;
    }
    __syncthreads();
#pragma unroll
    for (int i = 0; i < 32; i += 8) {
        int n = n0 + ty + i;
        W1t[(long)n * KP + k0 + tx] = f2bf(tile[tx][ty + i]);
    }
}

// ---------------------------------------------------------------------------
// Kernel 1: split-K GEMM partials. pout[ch][8192][256] = x @ W1 (chunk ch)
// Block: 512 thr (8 waves), tile BM=128 x BN=256, K-step 32, MFMA 16x16x32 bf16.
// Pipelined: double-buffered LDS, ONE barrier per K-step, loads for step s+1
// issued before the barrier of step s (reg-staged, stay in flight across
// s_barrier — T14 pattern). Keeps ~16 KB/CU of x in flight -> HBM BW floor.
// ---------------------------------------------------------------------------
__global__ __launch_bounds__(512, 2)
void gemm1(const float* __restrict__ x, const short* __restrict__ W1t,
           float* __restrict__ pout, int nch) {
    __shared__ short As[2][BM * 32];     // 2 x 8 KB   [m][k]
    __shared__ short Bs[2][BN * 32];     // 2 x 16 KB  [n][k] (B^T layout)

    int bid = blockIdx.x;
    int mb, ch;
    if (nch == 4) {
        // XCD-aware decode: chunk ch lives on one XCD pair so its 2.3 MB W1t
        // slice stays L2-resident. Bijective: bid = slot*8 + xcd.
        int xcd  = bid & 7;
        int slot = bid >> 3;             // 0..31
        ch = xcd >> 1;                   // 0..3
        mb = ((xcd & 1) << 5) | slot;    // 0..63
    } else {
        mb = bid % MBLK;
        ch = bid / MBLK;
    }
    int m0 = mb * BM;
    int s0 = (NSTEPS * ch) / nch;
    int s1 = (NSTEPS * (ch + 1)) / nch;

    int tid  = threadIdx.x;
    int wave = tid >> 6;
    int lane = tid & 63;
    int wr = wave >> 2, wc = wave & 3;
    int lrow = lane & 15;
    int lq   = lane >> 4;                // quad 0..3

    // staging address precompute (layouts identical to previous version;
    // LDS write offsets are linear in tid: A short4 @ tid*4(+2048), B int4 @ tid*8(+4096))
    int k4 = (tid & 7) << 2;                                   // 0..28 floats
    const float* xp0 = x + (long)(m0 + (tid >> 3)) * KREAL + k4;
    const float* xp1 = xp0 + (long)64 * KREAL;
    const short* bp0 = W1t + (long)(tid >> 2) * KP + ((tid & 3) << 3);
    const short* bp1 = bp0 + (long)128 * KP;

    frag_cd acc[4][4];
#pragma unroll
    for (int i = 0; i < 4; i++)
#pragma unroll
        for (int j = 0; j < 4; j++) acc[i][j] = (frag_cd)(0.f);

    float4 ra0, ra1;
    int4   rb0, rb1;
    {   // prologue: load step s0 into regs
        int kb = s0 * 32;
        bool ok = (kb + k4 + 4 <= KREAL);
        ra0 = ok ? *(const float4*)(xp0 + kb) : make_float4(0.f, 0.f, 0.f, 0.f);
        ra1 = ok ? *(const float4*)(xp1 + kb) : make_float4(0.f, 0.f, 0.f, 0.f);
        rb0 = *(const int4*)(bp0 + kb);      // W1t zero-padded to KP: always in-bounds
        rb1 = *(const int4*)(bp1 + kb);
    }

    int buf = 0;
    for (int s = s0; s < s1; ++s) {
        // (1) drain staged regs for step s -> LDS[buf]  (implicit vmcnt wait here)
        *(short4*)(&As[buf][tid * 4])        = cvt4(ra0);
        *(short4*)(&As[buf][tid * 4 + 2048]) = cvt4(ra1);
        *(int4*)(&Bs[buf][tid * 8])          = rb0;
        *(int4*)(&Bs[buf][tid * 8 + 4096])   = rb1;
        // (2) issue loads for step s+1 — in flight across the barrier + MFMA phase
        if (s + 1 < s1) {
            int kb = (s + 1) * 32;
            bool ok = (kb + k4 + 4 <= KREAL);
            ra0 = ok ? *(const float4*)(xp0 + kb) : make_float4(0.f, 0.f, 0.f, 0.f);
            ra1 = ok ? *(const float4*)(xp1 + kb) : make_float4(0.f, 0.f, 0.f, 0.f);
            rb0 = *(const int4*)(bp0 + kb);
            rb1 = *(const int4*)(bp1 + kb);
        }
        // (3) single barrier: LDS[buf] writes visible; reads of LDS[buf^1] from
        // step s-1 were drained before each wave's previous MFMA issue, so the
        // write to LDS[buf] two iterations from now is safe.
        __syncthreads();
        // (4) fragments + MFMA from LDS[buf]
        frag_ab af[4], bfr[4];
#pragma unroll
        for (int mt = 0; mt < 4; mt++)
            af[mt] = *(const frag_ab*)(&As[buf][(wr * 64 + mt * 16 + lrow) * 32 + lq * 8]);
#pragma unroll
        for (int nt = 0; nt < 4; nt++)
            bfr[nt] = *(const frag_ab*)(&Bs[buf][(wc * 64 + nt * 16 + lrow) * 32 + lq * 8]);
#pragma unroll
        for (int mt = 0; mt < 4; mt++)
#pragma unroll
            for (int nt = 0; nt < 4; nt++)
                acc[mt][nt] = __builtin_amdgcn_mfma_f32_16x16x32_bf16(
                    af[mt], bfr[nt], acc[mt][nt], 0, 0, 0);
        buf ^= 1;
    }

    // epilogue: D row = quad*4 + reg, col = lane&15 (m89-verified layout)
#pragma unroll
    for (int mt = 0; mt < 4; mt++)
#pragma unroll
        for (int nt = 0; nt < 4; nt++)
#pragma unroll
            for (int r = 0; r < 4; r++) {
                int row = m0 + wr * 64 + mt * 16 + lq * 4 + r;
                int col = wc * 64 + nt * 16 + lrow;
                pout[((long)ch * BATCH + row) * SDIM + col] = acc[mt][nt][r];
            }
}

// ---------------------------------------------------------------------------
// Kernel 2: per-sample pathway expert + drug head (fp32).
// ---------------------------------------------------------------------------
__global__ void stage2(const float* __restrict__ pout, const float* __restrict__ b1,
                       const float* __restrict__ Wp, const float* __restrict__ bp,
                       const float* __restrict__ Wd, const float* __restrict__ bd,
                       const int* __restrict__ drug_idx, const int* __restrict__ d2p,
                       float* __restrict__ out, int nch) {
    __shared__ float h[SDIM];
    __shared__ float red[2];
    int b = blockIdx.x;
    int t = threadIdx.x;                 // 0..127
    int drug = drug_idx[b];
    int p    = d2p[drug];

    for (int i = t; i < SDIM; i += 128) {
        float a = b1[i];
        for (int c = 0; c < nch; c++)
            a += pout[((long)c * BATCH + b) * SDIM + i];
        h[i] = fmaxf(a, 0.f);
    }
    __syncthreads();

    const float* wp = Wp + (long)p * SDIM * PDIM;
    float a = 0.f;
#pragma unroll 8
    for (int s = 0; s < SDIM; s++)
        a = fmaf(h[s], wp[s * PDIM + t], a);   // h[s] broadcast, wp coalesced
    a += bp[p * PDIM + t];
    a = fmaxf(a, 0.f);

    float v = a * Wd[drug * PDIM + t];
#pragma unroll
    for (int off = 32; off; off >>= 1) v += __shfl_down(v, off, 64);
    if ((t & 63) == 0) red[t >> 6] = v;
    __syncthreads();
    if (t == 0) out[b] = red[0] + red[1] + bd[drug];
}

// ---------------------------------------------------------------------------
extern "C" void kernel_launch(void* const* d_in, const int* in_sizes, int n_in,
                              void* d_out, int out_size, void* d_ws, size_t ws_size,
                              hipStream_t stream) {
    const float* x    = (const float*)d_in[0];
    const int*   drug = (const int*)d_in[1];
    const float* W1   = (const float*)d_in[2];
    const float* b1   = (const float*)d_in[3];
    const float* Wp   = (const float*)d_in[4];
    const float* bp   = (const float*)d_in[5];
    const float* Wd   = (const float*)d_in[6];
    const float* bd   = (const float*)d_in[7];
    const int*   d2p  = (const int*)d_in[8];
    float* out = (float*)d_out;

    size_t pchunk    = (size_t)BATCH * SDIM * sizeof(float);    // 8 MB per K-chunk
    size_t w1t_bytes = (size_t)SDIM * KP * sizeof(short);       // ~9.3 MB
    int nch = 4;
    if (ws_size < w1t_bytes + 4 * pchunk) {
        long avail = (long)ws_size - (long)w1t_bytes;
        nch = (int)(avail / (long)pchunk);
        if (nch < 1) nch = 1;
        if (nch > 4) nch = 4;
    }
    float* pout = (float*)d_ws;
    short* W1t  = (short*)((char*)d_ws + (size_t)nch * pchunk);

    hipLaunchKernelGGL(transpose_w1, dim3(NSTEPS, SDIM / 32), dim3(256), 0, stream,
                       W1, W1t);
    hipLaunchKernelGGL(gemm1, dim3(MBLK * nch), dim3(512), 0, stream,
                       x, W1t, pout, nch);
    hipLaunchKernelGGL(stage2, dim3(BATCH), dim3(128), 0, stream,
                       pout, b1, Wp, bp, Wd, bd, drug, d2p, out, nch);
}